// Round 5
// baseline (442.425 us; speedup 1.0000x reference)
//
#include <hip/hip_runtime.h>
#include <hip/hip_bf16.h>

typedef unsigned int   u32;
typedef unsigned short u16;
typedef unsigned char  u8;
typedef float f32x2 __attribute__((ext_vector_type(2)));
typedef float f32x4 __attribute__((ext_vector_type(4)));

#define N_NODES 50000
#define C_DIM   128
#define E_EDGES 1600000
#define NUM_IDX 2048

#define NS  196                    // node stripes of 256 (ceil(N/256))
#define GB  8                      // nodes per label-matmul block

// K1: label histogram (LDS-staged); blocks 0..7 also histogram `id` -> cnt[N]
__global__ void label_hist_kernel(const int* __restrict__ label, int* __restrict__ labCnt,
                                  const int* __restrict__ id, int* __restrict__ cnt) {
    __shared__ int h[8];
    if (threadIdx.x < 8) h[threadIdx.x] = 0;
    __syncthreads();
    int n = blockIdx.x * 256 + threadIdx.x;
    if (n < N_NODES) atomicAdd(&h[label[n]], 1);
    if (n < NUM_IDX) atomicAdd(&cnt[id[n]], 1);    // blocks 0..7 cover all 2048 ids
    __syncthreads();
    if (threadIdx.x < 8 && h[threadIdx.x] > 0) atomicAdd(&labCnt[threadIdx.x], h[threadIdx.x]);
}

// K2: edge degree histograms via direct global atomics (random across 200 KB -> low contention)
__global__ void edge_hist_kernel(const int* __restrict__ row, const int* __restrict__ col,
                                 int* __restrict__ rowDeg, int* __restrict__ colDeg) {
    int i = blockIdx.x * blockDim.x + threadIdx.x;
    int stride = gridDim.x * blockDim.x;
    for (int e = i; e < E_EDGES; e += stride) {
        atomicAdd(&colDeg[col[e]], 1);
        atomicAdd(&rowDeg[row[e]], 1);
    }
}

// K3: per-stripe sum of colDeg -> stripeSum; also dinv from rowDeg (fused)
__global__ void stripe_kernel(const int* __restrict__ colDeg, const int* __restrict__ rowDeg,
                              int* __restrict__ stripeSum, float* __restrict__ dinv) {
    __shared__ int sh[256];
    int t = threadIdx.x;
    int n = blockIdx.x * 256 + t;
    int v = (n < N_NODES) ? colDeg[n] : 0;
    if (n < N_NODES) dinv[n] = rsqrtf((float)(rowDeg[n] + 1));
    sh[t] = v;
    __syncthreads();
    for (int off = 128; off > 0; off >>= 1) {
        if (t < off) sh[t] += sh[t + off];
        __syncthreads();
    }
    if (t == 0) stripeSum[blockIdx.x] = sh[0];
}

// K4: 1-block exclusive scan of stripeSum -> stripeBase; also labCnt -> labCur
__global__ void stripe_scan_kernel(const int* __restrict__ stripeSum, int* __restrict__ stripeBase,
                                   const int* __restrict__ labCnt, int* __restrict__ labCur) {
    __shared__ int sc[256];
    int t = threadIdx.x;
    int v = (t < NS) ? stripeSum[t] : 0;
    sc[t] = v;
    __syncthreads();
    for (int off = 1; off < 256; off <<= 1) {
        int s = sc[t];
        int a = (t >= off) ? sc[t - off] : 0;
        __syncthreads();
        sc[t] = s + a;
        __syncthreads();
    }
    if (t < NS) stripeBase[t] = sc[t] - v;   // exclusive
    if (t == 0) {
        int run = 0;
        for (int i = 0; i < 8; ++i) { labCur[i] = run; run += labCnt[i]; }
    }
}

// K5: intra-stripe exclusive scan of colDeg + stripeBase -> start[], cur[]
__global__ void node_scan_kernel(const int* __restrict__ colDeg, const int* __restrict__ stripeBase,
                                 int* __restrict__ start, int* __restrict__ cur) {
    __shared__ int sc[256];
    int t = threadIdx.x;
    int b = blockIdx.x;
    int n = b * 256 + t;
    int v = (n < N_NODES) ? colDeg[n] : 0;
    sc[t] = v;
    __syncthreads();
    for (int off = 1; off < 256; off <<= 1) {
        int s = sc[t];
        int a = (t >= off) ? sc[t - off] : 0;
        __syncthreads();
        sc[t] = s + a;
        __syncthreads();
    }
    if (n < N_NODES) {
        int s = stripeBase[b] + sc[t] - v;
        start[n] = s;
        cur[n]   = s;
    }
    if (b == NS - 1 && t == 0) start[N_NODES] = E_EDGES;
}

// K6: compact nodes grouped by label (block-ranked, 8 global atomics per block)
__global__ void label_fill_kernel(const int* __restrict__ label, int* __restrict__ labCur,
                                  int* __restrict__ nodeByLabel) {
    __shared__ int h[8], base[8], c2[8];
    int t = threadIdx.x;
    if (t < 8) { h[t] = 0; c2[t] = 0; }
    __syncthreads();
    int n = blockIdx.x * 256 + t;
    int l = 0;
    if (n < N_NODES) { l = label[n]; atomicAdd(&h[l], 1); }
    __syncthreads();
    if (t < 8 && h[t] > 0) base[t] = atomicAdd(&labCur[t], h[t]);
    __syncthreads();
    if (n < N_NODES) {
        int pos = base[l] + atomicAdd(&c2[l], 1);
        nodeByLabel[pos] = n;
    }
}

// K7: scatter edges into CSR via per-col global cursors; srcrow holds full row id (u16, N<65536)
__global__ void scatter_kernel(const int* __restrict__ row, const int* __restrict__ col,
                               int* __restrict__ cur, u16* __restrict__ srcrow) {
    int i = blockIdx.x * blockDim.x + threadIdx.x;
    int stride = gridDim.x * blockDim.x;
    for (int e = i; e < E_EDGES; e += stride) {
        int pos = atomicAdd(&cur[col[e]], 1);
        srcrow[pos] = (u16)row[e];
    }
}

// K8: label-grouped node transform -> bf16 messages.
__global__ void node_msg_kernel(const float* __restrict__ x,
                                const int* __restrict__ cnt,
                                const int* __restrict__ label,
                                const float* __restrict__ dinv,
                                const float* __restrict__ W,
                                const float* __restrict__ Wid,
                                const int* __restrict__ nodeByLabel,
                                __hip_bfloat16* __restrict__ msgb) {
    __shared__ float xs[GB][C_DIM];
    __shared__ int nid[GB], lab[GB], cc[GB];
    int t = threadIdx.x;
    if (t < GB) {
        int n = nodeByLabel[blockIdx.x * GB + t];
        nid[t] = n; lab[t] = label[n]; cc[t] = cnt[n];
    }
    __syncthreads();
    #pragma unroll
    for (int g = 0; g < GB; ++g)
        xs[g][t] = __builtin_nontemporal_load(x + (size_t)nid[g] * C_DIM + t);
    __syncthreads();
    for (int g = 0; g < GB; ++g) {          // ego update (~4% of nodes)
        int c = cc[g];
        if (c > 0) {
            float acc = 0.f;
            #pragma unroll 8
            for (int k = 0; k < C_DIM; ++k) acc += xs[g][k] * W[k * C_DIM + t];
            __syncthreads();
            xs[g][t] += (float)c * acc;
            __syncthreads();
        }
    }
    float res[GB];
    #pragma unroll
    for (int g = 0; g < GB; ++g) res[g] = xs[g][t];
    if (lab[0] == lab[GB - 1]) {
        int L = lab[0];
        if (L > 0) {
            const float* Wl = Wid + (size_t)(L - 1) * C_DIM * C_DIM;
            float acc[GB];
            #pragma unroll
            for (int g = 0; g < GB; ++g) acc[g] = 0.f;
            for (int k = 0; k < C_DIM; ++k) {
                float w = Wl[k * C_DIM + t];
                #pragma unroll
                for (int g = 0; g < GB; ++g) acc[g] += xs[g][k] * w;
            }
            #pragma unroll
            for (int g = 0; g < GB; ++g) res[g] += acc[g];
        }
    } else {
        for (int g = 0; g < GB; ++g) {
            int L = lab[g];
            if (L > 0) {
                const float* Wl = Wid + (size_t)(L - 1) * C_DIM * C_DIM;
                float acc = 0.f;
                #pragma unroll 8
                for (int k = 0; k < C_DIM; ++k) acc += xs[g][k] * Wl[k * C_DIM + t];
                res[g] += acc;
            }
        }
    }
    #pragma unroll
    for (int g = 0; g < GB; ++g) {
        int n = nid[g];
        msgb[(size_t)n * C_DIM + t] = __float2bfloat16(dinv[n] * res[g]);
    }
}

// K9: gather + finalize. One wave per dest node; 4 edges in flight per wave.
// lane = (g, q): g = lane>>4 selects edge slot, q = lane&15 selects channel quad.
__global__ void gather_kernel(const int* __restrict__ start,
                              const u16* __restrict__ srcrow,
                              const float* __restrict__ dinv,
                              const u32* __restrict__ m32,   // bf16x2-packed msg
                              float* __restrict__ out) {
    int wid  = threadIdx.x >> 6;
    int lane = threadIdx.x & 63;
    int g = lane >> 4;
    int q = lane & 15;
    int c = blockIdx.x * 4 + wid;
    int e0 = start[c], e1 = start[c + 1];
    const uint4* m4 = (const uint4*)m32;   // one node = 16 uint4

    float a0[4], a1[4];
    #pragma unroll
    for (int k = 0; k < 4; ++k) { a0[k] = 0.f; a1[k] = 0.f; }

    #define ACC4(U)                                                          \
        a0[0] += __uint_as_float((U).x << 16); a1[0] += __uint_as_float((U).x & 0xffff0000u); \
        a0[1] += __uint_as_float((U).y << 16); a1[1] += __uint_as_float((U).y & 0xffff0000u); \
        a0[2] += __uint_as_float((U).z << 16); a1[2] += __uint_as_float((U).z & 0xffff0000u); \
        a0[3] += __uint_as_float((U).w << 16); a1[3] += __uint_as_float((U).w & 0xffff0000u);

    int e = e0;
    for (; e + 8 <= e1; e += 8) {
        u32 r0 = srcrow[e + g];
        u32 r1 = srcrow[e + 4 + g];
        uint4 u0 = m4[r0 * 16u + (u32)q];
        uint4 u1 = m4[r1 * 16u + (u32)q];
        ACC4(u0);
        ACC4(u1);
    }
    if (e + 4 <= e1) {
        u32 r0 = srcrow[e + g];
        uint4 u0 = m4[r0 * 16u + (u32)q];
        ACC4(u0);
        e += 4;
    }
    if (g == 0) {
        // self-loop message (counted once via edge-slot 0 only)
        uint4 us = m4[(u32)c * 16u + (u32)q];
        ACC4(us);
        // tail (< 4 remaining edges)
        for (; e < e1; ++e) {
            u32 r = srcrow[e];
            uint4 u = m4[r * 16u + (u32)q];
            ACC4(u);
        }
    }
    #undef ACC4

    // reduce the 4 edge-slot groups: lanes l, l^16, l^32, l^48 hold the same quad q
    #pragma unroll
    for (int k = 0; k < 4; ++k) {
        a0[k] += __shfl_xor(a0[k], 16);
        a0[k] += __shfl_xor(a0[k], 32);
        a1[k] += __shfl_xor(a1[k], 16);
        a1[k] += __shfl_xor(a1[k], 32);
    }

    if (lane < 16) {
        float di = dinv[c];
        f32x4 o0, o1;
        o0.x = di * a0[0]; o0.y = di * a1[0]; o0.z = di * a0[1]; o0.w = di * a1[1];
        o1.x = di * a0[2]; o1.y = di * a1[2]; o1.z = di * a0[3]; o1.w = di * a1[3];
        f32x4* op = (f32x4*)(out + ((size_t)c << 7)) + (q << 1);
        __builtin_nontemporal_store(o0, op);
        __builtin_nontemporal_store(o1, op + 1);
    }
}

extern "C" void kernel_launch(void* const* d_in, const int* in_sizes, int n_in,
                              void* d_out, int out_size, void* d_ws, size_t ws_size,
                              hipStream_t stream) {
    const float* x     = (const float*)d_in[0];
    const int*   edge  = (const int*)d_in[1];   // [2][E]
    const int*   id    = (const int*)d_in[2];
    const int*   label = (const int*)d_in[3];
    const float* W     = (const float*)d_in[4];
    const float* Wid   = (const float*)d_in[5];
    float*       out   = (float*)d_out;

    const int* row = edge;
    const int* col = edge + E_EDGES;

    // ws layout:
    // msgb[N*C] bf16 | srcrow[E] u16 | start[N+1] | cur[N] | stripeSum[256] |
    // stripeBase[256] | nodeByLabel[N] | dinv[N] f32 |
    // ZERO{ cnt[N] | colDeg[N] | rowDeg[N] | labCnt[8] | labCur[8] }
    __hip_bfloat16* msgb = (__hip_bfloat16*)d_ws;
    u16* srcrow      = (u16*)(msgb + (size_t)N_NODES * C_DIM);
    int* start       = (int*)(srcrow + E_EDGES);
    int* cur         = start + (N_NODES + 1);
    int* stripeSum   = cur + N_NODES;
    int* stripeBase  = stripeSum + 256;
    int* nodeByLabel = stripeBase + 256;
    float* dinv      = (float*)(nodeByLabel + N_NODES);
    int* cnt         = (int*)(dinv + N_NODES);
    int* colDeg      = cnt + N_NODES;
    int* rowDeg      = colDeg + N_NODES;
    int* labCnt      = rowDeg + N_NODES;
    int* labCur      = labCnt + 8;

    hipMemsetAsync(cnt, 0, ((size_t)3 * N_NODES + 16) * sizeof(int), stream);

    label_hist_kernel <<<196, 256, 0, stream>>>(label, labCnt, id, cnt);
    edge_hist_kernel  <<<2048, 256, 0, stream>>>(row, col, rowDeg, colDeg);
    stripe_kernel     <<<NS, 256, 0, stream>>>(colDeg, rowDeg, stripeSum, dinv);
    stripe_scan_kernel<<<1, 256, 0, stream>>>(stripeSum, stripeBase, labCnt, labCur);
    node_scan_kernel  <<<NS, 256, 0, stream>>>(colDeg, stripeBase, start, cur);
    label_fill_kernel <<<196, 256, 0, stream>>>(label, labCur, nodeByLabel);
    scatter_kernel    <<<2048, 256, 0, stream>>>(row, col, cur, srcrow);
    node_msg_kernel   <<<N_NODES / GB, C_DIM, 0, stream>>>(x, cnt, label, dinv, W, Wid,
                                                           nodeByLabel, msgb);
    gather_kernel     <<<N_NODES / 4, 256, 0, stream>>>(start, srcrow, dinv,
                                                        (const u32*)msgb, out);
}

// Round 6
// 387.885 us; speedup vs baseline: 1.1406x; 1.1406x over previous
//
#include <hip/hip_runtime.h>
#include <hip/hip_bf16.h>

typedef unsigned int   u32;
typedef unsigned short u16;
typedef unsigned char  u8;
typedef float f32x2 __attribute__((ext_vector_type(2)));
typedef float f32x4 __attribute__((ext_vector_type(4)));

#define N_NODES 50000
#define C_DIM   128
#define E_EDGES 1600000
#define NUM_IDX 2048

#define CPB 256                    // cols per coarse bucket (key >> 8)
#define NB  196                    // ceil(N/CPB)
#define CAP 9216                   // padded capacity per bucket (mean 8192, sigma ~90)
#define CHK 4096                   // edges per chunk
#define NP  391                    // ceil(E/CHK)
#define PT  512                    // threads for partition-family kernels
#define EPT 8                      // edges per thread in partition (CHK/PT)
#define GB  8                      // nodes per label-matmul block

// NOTE (round-5 lesson): device-scope global atomics on MI355X are HBM-side RMW
// (~32B write-through each; 3.2M atomics cost 129us at 100MB WRITE_SIZE).
// All histogram/cursor aggregation below stays in LDS; global atomics only for
// coarse per-block range reservation (196*2 per chunk-block max).

// K1: label histogram (LDS-staged); blocks 0..7 also histogram `id` -> cnt[N].
// Thread 0 of block b initializes bucket cursors to padded region bases.
__global__ void label_hist_kernel(const int* __restrict__ label, int* __restrict__ labCnt,
                                  const int* __restrict__ id, int* __restrict__ cnt,
                                  int* __restrict__ colCursor, int* __restrict__ rowCursor) {
    __shared__ int h[8];
    if (threadIdx.x < 8) h[threadIdx.x] = 0;
    __syncthreads();
    int n = blockIdx.x * 256 + threadIdx.x;
    if (n < N_NODES) atomicAdd(&h[label[n]], 1);
    if (n < NUM_IDX) atomicAdd(&cnt[id[n]], 1);    // blocks 0..7 cover all 2048 ids
    if (threadIdx.x == 0) {                        // 196 blocks == NB buckets
        colCursor[blockIdx.x] = blockIdx.x * CAP;
        rowCursor[blockIdx.x] = blockIdx.x * CAP;
    }
    __syncthreads();
    if (threadIdx.x < 8 && h[threadIdx.x] > 0) atomicAdd(&labCnt[threadIdx.x], h[threadIdx.x]);
}

// K2: tiny: labCnt -> labCur bases.
__global__ void label_base_kernel(const int* __restrict__ labCnt, int* __restrict__ labCur) {
    if (threadIdx.x == 0) {
        int run = 0;
        for (int i = 0; i < 8; ++i) { labCur[i] = run; run += labCnt[i]; }
    }
}

// K3: partition edges into padded bucket regions. Per block: LDS hist over its
// chunk (edges register-cached, static-indexed), one global atomicAdd per
// non-empty bucket to reserve a range, then write S ((row<<8)|(col&255)) and
// Sr (u8 row&255) via LDS cursors from the cached registers.
__global__ void partition_kernel(const int* __restrict__ row, const int* __restrict__ col,
                                 int* __restrict__ colCursor, int* __restrict__ rowCursor,
                                 u32* __restrict__ S, u8* __restrict__ Sr) {
    __shared__ int hc[NB], hr[NB], bc[NB], br[NB];
    int p = blockIdx.x;
    for (int i = threadIdx.x; i < NB; i += PT) { hc[i] = 0; hr[i] = 0; }
    __syncthreads();
    int e0 = p * CHK, e1 = min(e0 + CHK, E_EDGES);
    int rr[EPT], cc[EPT];
    #pragma unroll
    for (int i = 0; i < EPT; ++i) {
        int e = e0 + threadIdx.x + i * PT;
        if (e < e1) {
            int r = row[e], c = col[e];
            rr[i] = r; cc[i] = c;
            atomicAdd(&hc[c >> 8], 1);
            atomicAdd(&hr[r >> 8], 1);
        }
    }
    __syncthreads();
    for (int i = threadIdx.x; i < NB; i += PT) {
        bc[i] = (hc[i] > 0) ? atomicAdd(&colCursor[i], hc[i]) : 0;
        br[i] = (hr[i] > 0) ? atomicAdd(&rowCursor[i], hr[i]) : 0;
    }
    __syncthreads();
    #pragma unroll
    for (int i = 0; i < EPT; ++i) {
        int e = e0 + threadIdx.x + i * PT;
        if (e < e1) {
            int r = rr[i], c = cc[i];
            int pc = atomicAdd(&bc[c >> 8], 1);
            S[pc] = ((u32)r << 8) | (u32)(c & 255);
            int pr = atomicAdd(&br[r >> 8], 1);
            Sr[pr] = (u8)(r & 255);
        }
    }
}

// K4: compact nodes grouped by label (block-ranked, 8 global atomics per block)
__global__ void label_fill_kernel(const int* __restrict__ label, int* __restrict__ labCur,
                                  int* __restrict__ nodeByLabel) {
    __shared__ int h[8], base[8], c2[8];
    int t = threadIdx.x;
    if (t < 8) { h[t] = 0; c2[t] = 0; }
    __syncthreads();
    int n = blockIdx.x * 256 + t;
    int l = 0;
    if (n < N_NODES) { l = label[n]; atomicAdd(&h[l], 1); }
    __syncthreads();
    if (t < 8 && h[t] > 0) base[t] = atomicAdd(&labCur[t], h[t]);
    __syncthreads();
    if (n < N_NODES) {
        int pos = base[l] + atomicAdd(&c2[l], 1);
        nodeByLabel[pos] = n;
    }
}

// K5: fused fine-CSR (blocks 0..NB-1) + degree/dinv (blocks NB..2NB-1).
// Bucket b's edges live at [b*CAP, cursor[b]).
__global__ void csr_deg_kernel(const u32* __restrict__ S, const u8* __restrict__ Sr,
                               const int* __restrict__ colCursor, const int* __restrict__ rowCursor,
                               int* __restrict__ s_beg, int* __restrict__ s_end,
                               u16* __restrict__ srcrow, float* __restrict__ dinv) {
    __shared__ int h[CPB], cur[CPB], sc[CPB];
    int t = threadIdx.x;
    if (blockIdx.x >= NB) {
        // degree branch: LDS histogram of Sr bucket -> dinv
        int b = blockIdx.x - NB;
        if (t < CPB) h[t] = 0;
        __syncthreads();
        int e0 = b * CAP, e1 = rowCursor[b];
        for (int e = e0 + t; e < e1; e += PT) atomicAdd(&h[Sr[e]], 1);
        __syncthreads();
        if (t < CPB) {
            int n = b * CPB + t;
            if (n < N_NODES) dinv[n] = rsqrtf((float)(h[t] + 1));
        }
        return;
    }
    int b = blockIdx.x;
    if (t < CPB) h[t] = 0;
    __syncthreads();
    int e0 = b * CAP, e1 = colCursor[b];
    for (int e = e0 + t; e < e1; e += PT) atomicAdd(&h[S[e] & 255u], 1);
    __syncthreads();
    if (t < CPB) sc[t] = h[t];
    __syncthreads();
    for (int off = 1; off < CPB; off <<= 1) {
        int v = 0, a = 0;
        if (t < CPB) { v = sc[t]; a = (t >= off) ? sc[t - off] : 0; }
        __syncthreads();
        if (t < CPB) sc[t] = v + a;
        __syncthreads();
    }
    if (t < CPB) {
        int base = (t == 0) ? 0 : sc[t - 1];
        int gcol = b * CPB + t;
        if (gcol < N_NODES) {
            s_beg[gcol] = e0 + base;
            s_end[gcol] = e0 + base + h[t];
        }
        cur[t] = base;
    }
    __syncthreads();
    for (int e = e0 + t; e < e1; e += PT) {
        u32 v = S[e];
        int pos = atomicAdd(&cur[v & 255u], 1);
        srcrow[e0 + pos] = (u16)(v >> 8);
    }
}

// K6: label-grouped node transform -> bf16 messages.
// Inner loops k-unrolled x4 with f32x4 LDS reads (ds_read_b128): LDS-op count /4.
__global__ void node_msg_kernel(const float* __restrict__ x,
                                const int* __restrict__ cnt,
                                const int* __restrict__ label,
                                const float* __restrict__ dinv,
                                const float* __restrict__ W,
                                const float* __restrict__ Wid,
                                const int* __restrict__ nodeByLabel,
                                __hip_bfloat16* __restrict__ msgb) {
    __shared__ float xs[GB][C_DIM];
    __shared__ int nid[GB], lab[GB], cc[GB];
    int t = threadIdx.x;
    if (t < GB) {
        int n = nodeByLabel[blockIdx.x * GB + t];
        nid[t] = n; lab[t] = label[n]; cc[t] = cnt[n];
    }
    __syncthreads();
    #pragma unroll
    for (int g = 0; g < GB; ++g)
        xs[g][t] = __builtin_nontemporal_load(x + (size_t)nid[g] * C_DIM + t);
    __syncthreads();
    for (int g = 0; g < GB; ++g) {          // ego update (~4% of nodes)
        int c = cc[g];
        if (c > 0) {
            float acc = 0.f;
            for (int k = 0; k < C_DIM; k += 4) {
                f32x4 xv = *(const f32x4*)&xs[g][k];
                acc += xv.x * W[(k + 0) * C_DIM + t] + xv.y * W[(k + 1) * C_DIM + t]
                     + xv.z * W[(k + 2) * C_DIM + t] + xv.w * W[(k + 3) * C_DIM + t];
            }
            __syncthreads();
            xs[g][t] += (float)c * acc;
            __syncthreads();
        }
    }
    float res[GB];
    #pragma unroll
    for (int g = 0; g < GB; ++g) res[g] = xs[g][t];
    if (lab[0] == lab[GB - 1]) {
        int L = lab[0];
        if (L > 0) {
            const float* Wl = Wid + (size_t)(L - 1) * C_DIM * C_DIM;
            float acc[GB];
            #pragma unroll
            for (int g = 0; g < GB; ++g) acc[g] = 0.f;
            for (int k = 0; k < C_DIM; k += 4) {
                float w0 = Wl[(k + 0) * C_DIM + t];
                float w1 = Wl[(k + 1) * C_DIM + t];
                float w2 = Wl[(k + 2) * C_DIM + t];
                float w3 = Wl[(k + 3) * C_DIM + t];
                #pragma unroll
                for (int g = 0; g < GB; ++g) {
                    f32x4 xv = *(const f32x4*)&xs[g][k];
                    acc[g] += xv.x * w0 + xv.y * w1 + xv.z * w2 + xv.w * w3;
                }
            }
            #pragma unroll
            for (int g = 0; g < GB; ++g) res[g] += acc[g];
        }
    } else {
        for (int g = 0; g < GB; ++g) {
            int L = lab[g];
            if (L > 0) {
                const float* Wl = Wid + (size_t)(L - 1) * C_DIM * C_DIM;
                float acc = 0.f;
                for (int k = 0; k < C_DIM; k += 4) {
                    f32x4 xv = *(const f32x4*)&xs[g][k];
                    acc += xv.x * Wl[(k + 0) * C_DIM + t] + xv.y * Wl[(k + 1) * C_DIM + t]
                         + xv.z * Wl[(k + 2) * C_DIM + t] + xv.w * Wl[(k + 3) * C_DIM + t];
                }
                res[g] += acc;
            }
        }
    }
    #pragma unroll
    for (int g = 0; g < GB; ++g) {
        int n = nid[g];
        msgb[(size_t)n * C_DIM + t] = __float2bfloat16(dinv[n] * res[g]);
    }
}

// K7: gather + finalize. One wave per dest node; 4 edges in flight per wave.
// lane = (g, q): g = lane>>4 selects edge slot, q = lane&15 selects channel quad.
__global__ void gather_kernel(const int* __restrict__ s_beg, const int* __restrict__ s_end,
                              const u16* __restrict__ srcrow,
                              const float* __restrict__ dinv,
                              const u32* __restrict__ m32,   // bf16x2-packed msg
                              float* __restrict__ out) {
    int wid  = threadIdx.x >> 6;
    int lane = threadIdx.x & 63;
    int g = lane >> 4;
    int q = lane & 15;
    int c = blockIdx.x * 4 + wid;
    int e0 = s_beg[c], e1 = s_end[c];
    const uint4* m4 = (const uint4*)m32;   // one node = 16 uint4

    float a0[4], a1[4];
    #pragma unroll
    for (int k = 0; k < 4; ++k) { a0[k] = 0.f; a1[k] = 0.f; }

    #define ACC4(U)                                                          \
        a0[0] += __uint_as_float((U).x << 16); a1[0] += __uint_as_float((U).x & 0xffff0000u); \
        a0[1] += __uint_as_float((U).y << 16); a1[1] += __uint_as_float((U).y & 0xffff0000u); \
        a0[2] += __uint_as_float((U).z << 16); a1[2] += __uint_as_float((U).z & 0xffff0000u); \
        a0[3] += __uint_as_float((U).w << 16); a1[3] += __uint_as_float((U).w & 0xffff0000u);

    int e = e0;
    for (; e + 8 <= e1; e += 8) {
        u32 r0 = srcrow[e + g];
        u32 r1 = srcrow[e + 4 + g];
        uint4 u0 = m4[r0 * 16u + (u32)q];
        uint4 u1 = m4[r1 * 16u + (u32)q];
        ACC4(u0);
        ACC4(u1);
    }
    if (e + 4 <= e1) {
        u32 r0 = srcrow[e + g];
        uint4 u0 = m4[r0 * 16u + (u32)q];
        ACC4(u0);
        e += 4;
    }
    if (g == 0) {
        // self-loop message (counted once via edge-slot 0 only)
        uint4 us = m4[(u32)c * 16u + (u32)q];
        ACC4(us);
        // tail (< 4 remaining edges)
        for (; e < e1; ++e) {
            u32 r = srcrow[e];
            uint4 u = m4[r * 16u + (u32)q];
            ACC4(u);
        }
    }
    #undef ACC4

    // reduce the 4 edge-slot groups: lanes l, l^16, l^32, l^48 hold the same quad q
    #pragma unroll
    for (int k = 0; k < 4; ++k) {
        a0[k] += __shfl_xor(a0[k], 16);
        a0[k] += __shfl_xor(a0[k], 32);
        a1[k] += __shfl_xor(a1[k], 16);
        a1[k] += __shfl_xor(a1[k], 32);
    }

    if (lane < 16) {
        float di = dinv[c];
        f32x4 o0, o1;
        o0.x = di * a0[0]; o0.y = di * a1[0]; o0.z = di * a0[1]; o0.w = di * a1[1];
        o1.x = di * a0[2]; o1.y = di * a1[2]; o1.z = di * a0[3]; o1.w = di * a1[3];
        f32x4* op = (f32x4*)(out + ((size_t)c << 7)) + (q << 1);
        __builtin_nontemporal_store(o0, op);
        __builtin_nontemporal_store(o1, op + 1);
    }
}

extern "C" void kernel_launch(void* const* d_in, const int* in_sizes, int n_in,
                              void* d_out, int out_size, void* d_ws, size_t ws_size,
                              hipStream_t stream) {
    const float* x     = (const float*)d_in[0];
    const int*   edge  = (const int*)d_in[1];   // [2][E]
    const int*   id    = (const int*)d_in[2];
    const int*   label = (const int*)d_in[3];
    const float* W     = (const float*)d_in[4];
    const float* Wid   = (const float*)d_in[5];
    float*       out   = (float*)d_out;

    const int* row = edge;
    const int* col = edge + E_EDGES;

    // ws layout:
    // msgb[N*C] bf16 | S[NB*CAP] u32 | srcrow[NB*CAP] u16 | Sr[NB*CAP] u8 |
    // s_beg[N] | s_end[N] | colCursor[NB] | rowCursor[NB] |
    // nodeByLabel[N] | dinv[N] f32 | ZERO{ cnt[N] | labCnt[8] | labCur[8] }
    __hip_bfloat16* msgb = (__hip_bfloat16*)d_ws;
    u32* S           = (u32*)(msgb + (size_t)N_NODES * C_DIM);
    u16* srcrow      = (u16*)(S + (size_t)NB * CAP);
    u8*  Sr          = (u8*)(srcrow + (size_t)NB * CAP);
    int* s_beg       = (int*)(Sr + (size_t)NB * CAP);
    int* s_end       = s_beg + N_NODES;
    int* colCursor   = s_end + N_NODES;
    int* rowCursor   = colCursor + NB;
    int* nodeByLabel = rowCursor + NB;
    float* dinv      = (float*)(nodeByLabel + N_NODES);
    int* cnt         = (int*)(dinv + N_NODES);
    int* labCnt      = cnt + N_NODES;
    int* labCur      = labCnt + 8;

    hipMemsetAsync(cnt, 0, ((size_t)N_NODES + 16) * sizeof(int), stream);

    label_hist_kernel <<<196, 256, 0, stream>>>(label, labCnt, id, cnt, colCursor, rowCursor);
    label_base_kernel <<<1, 64, 0, stream>>>(labCnt, labCur);
    partition_kernel  <<<NP, PT, 0, stream>>>(row, col, colCursor, rowCursor, S, Sr);
    label_fill_kernel <<<196, 256, 0, stream>>>(label, labCur, nodeByLabel);
    csr_deg_kernel    <<<2 * NB, PT, 0, stream>>>(S, Sr, colCursor, rowCursor,
                                                  s_beg, s_end, srcrow, dinv);
    node_msg_kernel   <<<N_NODES / GB, C_DIM, 0, stream>>>(x, cnt, label, dinv, W, Wid,
                                                           nodeByLabel, msgb);
    gather_kernel     <<<N_NODES / 4, 256, 0, stream>>>(s_beg, s_end, srcrow, dinv,
                                                        (const u32*)msgb, out);
}

// Round 7
// 233.860 us; speedup vs baseline: 1.8918x; 1.6586x over previous
//
#include <hip/hip_runtime.h>
#include <hip/hip_bf16.h>

typedef unsigned int   u32;
typedef unsigned short u16;
typedef unsigned char  u8;
typedef float f32x2 __attribute__((ext_vector_type(2)));
typedef float f32x4 __attribute__((ext_vector_type(4)));

#define N_NODES 50000
#define C_DIM   128
#define E_EDGES 1600000
#define NUM_IDX 2048

#define CPB 256                    // cols per coarse bucket (key >> 8)
#define NB  196                    // ceil(N/CPB)
#define CAP 9216                   // padded capacity per bucket (mean 8192, sigma ~90)
#define CHK 4096                   // edges per chunk
#define NP  391                    // ceil(E/CHK)
#define PT  512                    // threads for partition-family kernels
#define EPT 8                      // edges per thread in partition (CHK/PT)
#define GB  8                      // nodes per label-matmul block

// LESSONS (journal):
// r5: device-scope global atomics on MI355X are HBM-side RMW (~32B write each;
//     3.2M atomics = 129us, WRITE_SIZE 100MB). Keep histograms in LDS.
// r6: f32x4-casting LDS reads inside GB x k double-unrolled loops spills the
//     accumulator state to scratch (WRITE_SIZE 443MB, 4-5x slower). Keep
//     node_msg's scalar LDS reads; verify numRegs before any such rewrite.

// K1: label histogram (LDS-staged); blocks 0..7 also histogram `id` -> cnt[N].
// Thread 0 of block b initializes bucket cursors to padded region bases.
__global__ void label_hist_kernel(const int* __restrict__ label, int* __restrict__ labCnt,
                                  const int* __restrict__ id, int* __restrict__ cnt,
                                  int* __restrict__ colCursor, int* __restrict__ rowCursor) {
    __shared__ int h[8];
    if (threadIdx.x < 8) h[threadIdx.x] = 0;
    __syncthreads();
    int n = blockIdx.x * 256 + threadIdx.x;
    if (n < N_NODES) atomicAdd(&h[label[n]], 1);
    if (n < NUM_IDX) atomicAdd(&cnt[id[n]], 1);    // blocks 0..7 cover all 2048 ids
    if (threadIdx.x == 0) {                        // 196 blocks == NB buckets
        colCursor[blockIdx.x] = blockIdx.x * CAP;
        rowCursor[blockIdx.x] = blockIdx.x * CAP;
    }
    __syncthreads();
    if (threadIdx.x < 8 && h[threadIdx.x] > 0) atomicAdd(&labCnt[threadIdx.x], h[threadIdx.x]);
}

// K2: tiny: labCnt -> labCur bases.
__global__ void label_base_kernel(const int* __restrict__ labCnt, int* __restrict__ labCur) {
    if (threadIdx.x == 0) {
        int run = 0;
        for (int i = 0; i < 8; ++i) { labCur[i] = run; run += labCnt[i]; }
    }
}

// K3: partition edges into padded bucket regions. Per block: LDS hist over its
// chunk (edges register-cached, static-indexed), one global atomicAdd per
// non-empty bucket to reserve a range, then write S ((row<<8)|(col&255)) and
// Sr (u8 row&255) via LDS cursors from the cached registers.
__global__ void partition_kernel(const int* __restrict__ row, const int* __restrict__ col,
                                 int* __restrict__ colCursor, int* __restrict__ rowCursor,
                                 u32* __restrict__ S, u8* __restrict__ Sr) {
    __shared__ int hc[NB], hr[NB], bc[NB], br[NB];
    int p = blockIdx.x;
    for (int i = threadIdx.x; i < NB; i += PT) { hc[i] = 0; hr[i] = 0; }
    __syncthreads();
    int e0 = p * CHK, e1 = min(e0 + CHK, E_EDGES);
    int rr[EPT], cc[EPT];
    #pragma unroll
    for (int i = 0; i < EPT; ++i) {
        int e = e0 + threadIdx.x + i * PT;
        if (e < e1) {
            int r = row[e], c = col[e];
            rr[i] = r; cc[i] = c;
            atomicAdd(&hc[c >> 8], 1);
            atomicAdd(&hr[r >> 8], 1);
        }
    }
    __syncthreads();
    for (int i = threadIdx.x; i < NB; i += PT) {
        bc[i] = (hc[i] > 0) ? atomicAdd(&colCursor[i], hc[i]) : 0;
        br[i] = (hr[i] > 0) ? atomicAdd(&rowCursor[i], hr[i]) : 0;
    }
    __syncthreads();
    #pragma unroll
    for (int i = 0; i < EPT; ++i) {
        int e = e0 + threadIdx.x + i * PT;
        if (e < e1) {
            int r = rr[i], c = cc[i];
            int pc = atomicAdd(&bc[c >> 8], 1);
            S[pc] = ((u32)r << 8) | (u32)(c & 255);
            int pr = atomicAdd(&br[r >> 8], 1);
            Sr[pr] = (u8)(r & 255);
        }
    }
}

// K4: compact nodes grouped by label (block-ranked, 8 global atomics per block)
__global__ void label_fill_kernel(const int* __restrict__ label, int* __restrict__ labCur,
                                  int* __restrict__ nodeByLabel) {
    __shared__ int h[8], base[8], c2[8];
    int t = threadIdx.x;
    if (t < 8) { h[t] = 0; c2[t] = 0; }
    __syncthreads();
    int n = blockIdx.x * 256 + t;
    int l = 0;
    if (n < N_NODES) { l = label[n]; atomicAdd(&h[l], 1); }
    __syncthreads();
    if (t < 8 && h[t] > 0) base[t] = atomicAdd(&labCur[t], h[t]);
    __syncthreads();
    if (n < N_NODES) {
        int pos = base[l] + atomicAdd(&c2[l], 1);
        nodeByLabel[pos] = n;
    }
}

// K5: fused fine-CSR (blocks 0..NB-1) + degree/dinv (blocks NB..2NB-1).
// Bucket b's edges live at [b*CAP, cursor[b]).
__global__ void csr_deg_kernel(const u32* __restrict__ S, const u8* __restrict__ Sr,
                               const int* __restrict__ colCursor, const int* __restrict__ rowCursor,
                               int* __restrict__ s_beg, int* __restrict__ s_end,
                               u16* __restrict__ srcrow, float* __restrict__ dinv) {
    __shared__ int h[CPB], cur[CPB], sc[CPB];
    int t = threadIdx.x;
    if (blockIdx.x >= NB) {
        // degree branch: LDS histogram of Sr bucket -> dinv
        int b = blockIdx.x - NB;
        if (t < CPB) h[t] = 0;
        __syncthreads();
        int e0 = b * CAP, e1 = rowCursor[b];
        for (int e = e0 + t; e < e1; e += PT) atomicAdd(&h[Sr[e]], 1);
        __syncthreads();
        if (t < CPB) {
            int n = b * CPB + t;
            if (n < N_NODES) dinv[n] = rsqrtf((float)(h[t] + 1));
        }
        return;
    }
    int b = blockIdx.x;
    if (t < CPB) h[t] = 0;
    __syncthreads();
    int e0 = b * CAP, e1 = colCursor[b];
    for (int e = e0 + t; e < e1; e += PT) atomicAdd(&h[S[e] & 255u], 1);
    __syncthreads();
    if (t < CPB) sc[t] = h[t];
    __syncthreads();
    for (int off = 1; off < CPB; off <<= 1) {
        int v = 0, a = 0;
        if (t < CPB) { v = sc[t]; a = (t >= off) ? sc[t - off] : 0; }
        __syncthreads();
        if (t < CPB) sc[t] = v + a;
        __syncthreads();
    }
    if (t < CPB) {
        int base = (t == 0) ? 0 : sc[t - 1];
        int gcol = b * CPB + t;
        if (gcol < N_NODES) {
            s_beg[gcol] = e0 + base;
            s_end[gcol] = e0 + base + h[t];
        }
        cur[t] = base;
    }
    __syncthreads();
    for (int e = e0 + t; e < e1; e += PT) {
        u32 v = S[e];
        int pos = atomicAdd(&cur[v & 255u], 1);
        srcrow[e0 + pos] = (u16)(v >> 8);
    }
}

// K6: label-grouped node transform -> bf16 messages. (round-4 body: scalar LDS
// reads — do NOT vectorize xs reads, causes scratch spill; see r6 lesson)
__global__ void node_msg_kernel(const float* __restrict__ x,
                                const int* __restrict__ cnt,
                                const int* __restrict__ label,
                                const float* __restrict__ dinv,
                                const float* __restrict__ W,
                                const float* __restrict__ Wid,
                                const int* __restrict__ nodeByLabel,
                                __hip_bfloat16* __restrict__ msgb) {
    __shared__ float xs[GB][C_DIM];
    __shared__ int nid[GB], lab[GB], cc[GB];
    int t = threadIdx.x;
    if (t < GB) {
        int n = nodeByLabel[blockIdx.x * GB + t];
        nid[t] = n; lab[t] = label[n]; cc[t] = cnt[n];
    }
    __syncthreads();
    #pragma unroll
    for (int g = 0; g < GB; ++g)
        xs[g][t] = __builtin_nontemporal_load(x + (size_t)nid[g] * C_DIM + t);
    __syncthreads();
    for (int g = 0; g < GB; ++g) {          // ego update (~4% of nodes)
        int c = cc[g];
        if (c > 0) {
            float acc = 0.f;
            #pragma unroll 8
            for (int k = 0; k < C_DIM; ++k) acc += xs[g][k] * W[k * C_DIM + t];
            __syncthreads();
            xs[g][t] += (float)c * acc;
            __syncthreads();
        }
    }
    float res[GB];
    #pragma unroll
    for (int g = 0; g < GB; ++g) res[g] = xs[g][t];
    if (lab[0] == lab[GB - 1]) {
        int L = lab[0];
        if (L > 0) {
            const float* Wl = Wid + (size_t)(L - 1) * C_DIM * C_DIM;
            float acc[GB];
            #pragma unroll
            for (int g = 0; g < GB; ++g) acc[g] = 0.f;
            for (int k = 0; k < C_DIM; ++k) {
                float w = Wl[k * C_DIM + t];
                #pragma unroll
                for (int g = 0; g < GB; ++g) acc[g] += xs[g][k] * w;
            }
            #pragma unroll
            for (int g = 0; g < GB; ++g) res[g] += acc[g];
        }
    } else {
        for (int g = 0; g < GB; ++g) {
            int L = lab[g];
            if (L > 0) {
                const float* Wl = Wid + (size_t)(L - 1) * C_DIM * C_DIM;
                float acc = 0.f;
                #pragma unroll 8
                for (int k = 0; k < C_DIM; ++k) acc += xs[g][k] * Wl[k * C_DIM + t];
                res[g] += acc;
            }
        }
    }
    #pragma unroll
    for (int g = 0; g < GB; ++g) {
        int n = nid[g];
        msgb[(size_t)n * C_DIM + t] = __float2bfloat16(dinv[n] * res[g]);
    }
}

// K7: gather + finalize. One wave per dest node; 4 edges in flight per wave.
// lane = (g, q): g = lane>>4 selects edge slot, q = lane&15 selects channel quad.
__global__ void gather_kernel(const int* __restrict__ s_beg, const int* __restrict__ s_end,
                              const u16* __restrict__ srcrow,
                              const float* __restrict__ dinv,
                              const u32* __restrict__ m32,   // bf16x2-packed msg
                              float* __restrict__ out) {
    int wid  = threadIdx.x >> 6;
    int lane = threadIdx.x & 63;
    int g = lane >> 4;
    int q = lane & 15;
    int c = blockIdx.x * 4 + wid;
    int e0 = s_beg[c], e1 = s_end[c];
    const uint4* m4 = (const uint4*)m32;   // one node = 16 uint4

    float a0[4], a1[4];
    #pragma unroll
    for (int k = 0; k < 4; ++k) { a0[k] = 0.f; a1[k] = 0.f; }

    #define ACC4(U)                                                          \
        a0[0] += __uint_as_float((U).x << 16); a1[0] += __uint_as_float((U).x & 0xffff0000u); \
        a0[1] += __uint_as_float((U).y << 16); a1[1] += __uint_as_float((U).y & 0xffff0000u); \
        a0[2] += __uint_as_float((U).z << 16); a1[2] += __uint_as_float((U).z & 0xffff0000u); \
        a0[3] += __uint_as_float((U).w << 16); a1[3] += __uint_as_float((U).w & 0xffff0000u);

    int e = e0;
    for (; e + 8 <= e1; e += 8) {
        u32 r0 = srcrow[e + g];
        u32 r1 = srcrow[e + 4 + g];
        uint4 u0 = m4[r0 * 16u + (u32)q];
        uint4 u1 = m4[r1 * 16u + (u32)q];
        ACC4(u0);
        ACC4(u1);
    }
    if (e + 4 <= e1) {
        u32 r0 = srcrow[e + g];
        uint4 u0 = m4[r0 * 16u + (u32)q];
        ACC4(u0);
        e += 4;
    }
    if (g == 0) {
        // self-loop message (counted once via edge-slot 0 only)
        uint4 us = m4[(u32)c * 16u + (u32)q];
        ACC4(us);
        // tail (< 4 remaining edges)
        for (; e < e1; ++e) {
            u32 r = srcrow[e];
            uint4 u = m4[r * 16u + (u32)q];
            ACC4(u);
        }
    }
    #undef ACC4

    // reduce the 4 edge-slot groups: lanes l, l^16, l^32, l^48 hold the same quad q
    #pragma unroll
    for (int k = 0; k < 4; ++k) {
        a0[k] += __shfl_xor(a0[k], 16);
        a0[k] += __shfl_xor(a0[k], 32);
        a1[k] += __shfl_xor(a1[k], 16);
        a1[k] += __shfl_xor(a1[k], 32);
    }

    if (lane < 16) {
        float di = dinv[c];
        f32x4 o0, o1;
        o0.x = di * a0[0]; o0.y = di * a1[0]; o0.z = di * a0[1]; o0.w = di * a1[1];
        o1.x = di * a0[2]; o1.y = di * a1[2]; o1.z = di * a0[3]; o1.w = di * a1[3];
        f32x4* op = (f32x4*)(out + ((size_t)c << 7)) + (q << 1);
        __builtin_nontemporal_store(o0, op);
        __builtin_nontemporal_store(o1, op + 1);
    }
}

extern "C" void kernel_launch(void* const* d_in, const int* in_sizes, int n_in,
                              void* d_out, int out_size, void* d_ws, size_t ws_size,
                              hipStream_t stream) {
    const float* x     = (const float*)d_in[0];
    const int*   edge  = (const int*)d_in[1];   // [2][E]
    const int*   id    = (const int*)d_in[2];
    const int*   label = (const int*)d_in[3];
    const float* W     = (const float*)d_in[4];
    const float* Wid   = (const float*)d_in[5];
    float*       out   = (float*)d_out;

    const int* row = edge;
    const int* col = edge + E_EDGES;

    // ws layout:
    // msgb[N*C] bf16 | S[NB*CAP] u32 | srcrow[NB*CAP] u16 | Sr[NB*CAP] u8 |
    // s_beg[N] | s_end[N] | colCursor[NB] | rowCursor[NB] |
    // nodeByLabel[N] | dinv[N] f32 | ZERO{ cnt[N] | labCnt[8] | labCur[8] }
    __hip_bfloat16* msgb = (__hip_bfloat16*)d_ws;
    u32* S           = (u32*)(msgb + (size_t)N_NODES * C_DIM);
    u16* srcrow      = (u16*)(S + (size_t)NB * CAP);
    u8*  Sr          = (u8*)(srcrow + (size_t)NB * CAP);
    int* s_beg       = (int*)(Sr + (size_t)NB * CAP);
    int* s_end       = s_beg + N_NODES;
    int* colCursor   = s_end + N_NODES;
    int* rowCursor   = colCursor + NB;
    int* nodeByLabel = rowCursor + NB;
    float* dinv      = (float*)(nodeByLabel + N_NODES);
    int* cnt         = (int*)(dinv + N_NODES);
    int* labCnt      = cnt + N_NODES;
    int* labCur      = labCnt + 8;

    hipMemsetAsync(cnt, 0, ((size_t)N_NODES + 16) * sizeof(int), stream);

    label_hist_kernel <<<196, 256, 0, stream>>>(label, labCnt, id, cnt, colCursor, rowCursor);
    label_base_kernel <<<1, 64, 0, stream>>>(labCnt, labCur);
    partition_kernel  <<<NP, PT, 0, stream>>>(row, col, colCursor, rowCursor, S, Sr);
    label_fill_kernel <<<196, 256, 0, stream>>>(label, labCur, nodeByLabel);
    csr_deg_kernel    <<<2 * NB, PT, 0, stream>>>(S, Sr, colCursor, rowCursor,
                                                  s_beg, s_end, srcrow, dinv);
    node_msg_kernel   <<<N_NODES / GB, C_DIM, 0, stream>>>(x, cnt, label, dinv, W, Wid,
                                                           nodeByLabel, msgb);
    gather_kernel     <<<N_NODES / 4, 256, 0, stream>>>(s_beg, s_end, srcrow, dinv,
                                                        (const u32*)msgb, out);
}

// Round 8
// 231.121 us; speedup vs baseline: 1.9143x; 1.0119x over previous
//
#include <hip/hip_runtime.h>
#include <hip/hip_bf16.h>

typedef unsigned int   u32;
typedef unsigned short u16;
typedef unsigned char  u8;
typedef float f32x2 __attribute__((ext_vector_type(2)));
typedef float f32x4 __attribute__((ext_vector_type(4)));

#define N_NODES 50000
#define C_DIM   128
#define E_EDGES 1600000
#define NUM_IDX 2048

#define CPB 256                    // cols per coarse bucket (key >> 8)
#define NB  196                    // ceil(N/CPB)
#define CAP 9216                   // padded capacity per bucket (mean 8192, sigma ~90)
#define CHK 4096                   // edges per chunk
#define NP  391                    // ceil(E/CHK)
#define PT  512                    // threads for partition-family kernels
#define EPT 8                      // edges per thread in partition (CHK/PT)
#define GB  8                      // nodes per label-matmul block

// LESSONS (journal):
// r5: device-scope global atomics on MI355X are HBM-side RMW (~32B write each;
//     3.2M atomics = 129us, WRITE_SIZE 100MB). Keep histograms in LDS.
// r6: f32x4-casting per-g LDS reads inside GB x k double-unrolled loops spills
//     accumulator state to scratch (WRITE_SIZE 443MB, 4-5x slower).
// r7: node_msg is LDS-issue bound (1 ds_read_b32 per FMA). Fix = k-major
//     transposed staging (xs_T[k][g]) so one aligned 2x ds_read_b128 broadcast
//     serves all 8 g per k. Low register pressure, no per-g vector casts.

// K1: label histogram (LDS-staged); blocks 0..7 also histogram `id` -> cnt[N].
// Thread 0 of block b initializes bucket cursors to padded region bases.
__global__ void label_hist_kernel(const int* __restrict__ label, int* __restrict__ labCnt,
                                  const int* __restrict__ id, int* __restrict__ cnt,
                                  int* __restrict__ colCursor, int* __restrict__ rowCursor) {
    __shared__ int h[8];
    if (threadIdx.x < 8) h[threadIdx.x] = 0;
    __syncthreads();
    int n = blockIdx.x * 256 + threadIdx.x;
    if (n < N_NODES) atomicAdd(&h[label[n]], 1);
    if (n < NUM_IDX) atomicAdd(&cnt[id[n]], 1);    // blocks 0..7 cover all 2048 ids
    if (threadIdx.x == 0) {                        // 196 blocks == NB buckets
        colCursor[blockIdx.x] = blockIdx.x * CAP;
        rowCursor[blockIdx.x] = blockIdx.x * CAP;
    }
    __syncthreads();
    if (threadIdx.x < 8 && h[threadIdx.x] > 0) atomicAdd(&labCnt[threadIdx.x], h[threadIdx.x]);
}

// K2: tiny: labCnt -> labCur bases.
__global__ void label_base_kernel(const int* __restrict__ labCnt, int* __restrict__ labCur) {
    if (threadIdx.x == 0) {
        int run = 0;
        for (int i = 0; i < 8; ++i) { labCur[i] = run; run += labCnt[i]; }
    }
}

// K3: partition edges into padded bucket regions. Per block: LDS hist over its
// chunk (edges register-cached, static-indexed), one global atomicAdd per
// non-empty bucket to reserve a range, then write S ((row<<8)|(col&255)) and
// Sr (u8 row&255) via LDS cursors from the cached registers.
__global__ void partition_kernel(const int* __restrict__ row, const int* __restrict__ col,
                                 int* __restrict__ colCursor, int* __restrict__ rowCursor,
                                 u32* __restrict__ S, u8* __restrict__ Sr) {
    __shared__ int hc[NB], hr[NB], bc[NB], br[NB];
    int p = blockIdx.x;
    for (int i = threadIdx.x; i < NB; i += PT) { hc[i] = 0; hr[i] = 0; }
    __syncthreads();
    int e0 = p * CHK, e1 = min(e0 + CHK, E_EDGES);
    int rr[EPT], cc[EPT];
    #pragma unroll
    for (int i = 0; i < EPT; ++i) {
        int e = e0 + threadIdx.x + i * PT;
        if (e < e1) {
            int r = row[e], c = col[e];
            rr[i] = r; cc[i] = c;
            atomicAdd(&hc[c >> 8], 1);
            atomicAdd(&hr[r >> 8], 1);
        }
    }
    __syncthreads();
    for (int i = threadIdx.x; i < NB; i += PT) {
        bc[i] = (hc[i] > 0) ? atomicAdd(&colCursor[i], hc[i]) : 0;
        br[i] = (hr[i] > 0) ? atomicAdd(&rowCursor[i], hr[i]) : 0;
    }
    __syncthreads();
    #pragma unroll
    for (int i = 0; i < EPT; ++i) {
        int e = e0 + threadIdx.x + i * PT;
        if (e < e1) {
            int r = rr[i], c = cc[i];
            int pc = atomicAdd(&bc[c >> 8], 1);
            S[pc] = ((u32)r << 8) | (u32)(c & 255);
            int pr = atomicAdd(&br[r >> 8], 1);
            Sr[pr] = (u8)(r & 255);
        }
    }
}

// K4: compact nodes grouped by label (block-ranked, 8 global atomics per block)
__global__ void label_fill_kernel(const int* __restrict__ label, int* __restrict__ labCur,
                                  int* __restrict__ nodeByLabel) {
    __shared__ int h[8], base[8], c2[8];
    int t = threadIdx.x;
    if (t < 8) { h[t] = 0; c2[t] = 0; }
    __syncthreads();
    int n = blockIdx.x * 256 + t;
    int l = 0;
    if (n < N_NODES) { l = label[n]; atomicAdd(&h[l], 1); }
    __syncthreads();
    if (t < 8 && h[t] > 0) base[t] = atomicAdd(&labCur[t], h[t]);
    __syncthreads();
    if (n < N_NODES) {
        int pos = base[l] + atomicAdd(&c2[l], 1);
        nodeByLabel[pos] = n;
    }
}

// K5: fused fine-CSR (blocks 0..NB-1) + degree/dinv (blocks NB..2NB-1).
// Bucket b's edges live at [b*CAP, cursor[b]).
__global__ void csr_deg_kernel(const u32* __restrict__ S, const u8* __restrict__ Sr,
                               const int* __restrict__ colCursor, const int* __restrict__ rowCursor,
                               int* __restrict__ s_beg, int* __restrict__ s_end,
                               u16* __restrict__ srcrow, float* __restrict__ dinv) {
    __shared__ int h[CPB], cur[CPB], sc[CPB];
    int t = threadIdx.x;
    if (blockIdx.x >= NB) {
        // degree branch: LDS histogram of Sr bucket -> dinv
        int b = blockIdx.x - NB;
        if (t < CPB) h[t] = 0;
        __syncthreads();
        int e0 = b * CAP, e1 = rowCursor[b];
        for (int e = e0 + t; e < e1; e += PT) atomicAdd(&h[Sr[e]], 1);
        __syncthreads();
        if (t < CPB) {
            int n = b * CPB + t;
            if (n < N_NODES) dinv[n] = rsqrtf((float)(h[t] + 1));
        }
        return;
    }
    int b = blockIdx.x;
    if (t < CPB) h[t] = 0;
    __syncthreads();
    int e0 = b * CAP, e1 = colCursor[b];
    for (int e = e0 + t; e < e1; e += PT) atomicAdd(&h[S[e] & 255u], 1);
    __syncthreads();
    if (t < CPB) sc[t] = h[t];
    __syncthreads();
    for (int off = 1; off < CPB; off <<= 1) {
        int v = 0, a = 0;
        if (t < CPB) { v = sc[t]; a = (t >= off) ? sc[t - off] : 0; }
        __syncthreads();
        if (t < CPB) sc[t] = v + a;
        __syncthreads();
    }
    if (t < CPB) {
        int base = (t == 0) ? 0 : sc[t - 1];
        int gcol = b * CPB + t;
        if (gcol < N_NODES) {
            s_beg[gcol] = e0 + base;
            s_end[gcol] = e0 + base + h[t];
        }
        cur[t] = base;
    }
    __syncthreads();
    for (int e = e0 + t; e < e1; e += PT) {
        u32 v = S[e];
        int pos = atomicAdd(&cur[v & 255u], 1);
        srcrow[e0 + pos] = (u16)(v >> 8);
    }
}

// K6: label-grouped node transform -> bf16 messages.
// k-major transposed staging: xs_T[k][g]. Uniform-label fast path reads
// xs_T[k][0..7] as two aligned f32x4 broadcasts (2 ds_read_b128 per k for all
// 8 g) instead of 8 ds_read_b32. Low live-register count -> no scratch (r6).
__global__ void node_msg_kernel(const float* __restrict__ x,
                                const int* __restrict__ cnt,
                                const int* __restrict__ label,
                                const float* __restrict__ dinv,
                                const float* __restrict__ W,
                                const float* __restrict__ Wid,
                                const int* __restrict__ nodeByLabel,
                                __hip_bfloat16* __restrict__ msgb) {
    __shared__ float xsT[C_DIM][GB];       // [k][g], 4 KB
    __shared__ int nid[GB], lab[GB], cc[GB];
    int t = threadIdx.x;
    if (t < GB) {
        int n = nodeByLabel[blockIdx.x * GB + t];
        nid[t] = n; lab[t] = label[n]; cc[t] = cnt[n];
    }
    __syncthreads();
    #pragma unroll
    for (int g = 0; g < GB; ++g)
        xsT[t][g] = __builtin_nontemporal_load(x + (size_t)nid[g] * C_DIM + t);
    __syncthreads();
    for (int g = 0; g < GB; ++g) {          // ego update (~4% of nodes)
        int c = cc[g];
        if (c > 0) {
            float acc = 0.f;
            #pragma unroll 8
            for (int k = 0; k < C_DIM; ++k) acc += xsT[k][g] * W[k * C_DIM + t];
            __syncthreads();
            xsT[t][g] += (float)c * acc;
            __syncthreads();
        }
    }
    float res[GB];
    #pragma unroll
    for (int g = 0; g < GB; ++g) res[g] = xsT[t][g];
    if (lab[0] == lab[GB - 1]) {
        int L = lab[0];
        if (L > 0) {
            const float* Wl = Wid + (size_t)(L - 1) * C_DIM * C_DIM;
            float acc[GB];
            #pragma unroll
            for (int g = 0; g < GB; ++g) acc[g] = 0.f;
            for (int k = 0; k < C_DIM; ++k) {
                float w = Wl[k * C_DIM + t];
                f32x4 xv0 = *(const f32x4*)&xsT[k][0];   // broadcast b128
                f32x4 xv1 = *(const f32x4*)&xsT[k][4];   // broadcast b128
                acc[0] += xv0.x * w; acc[1] += xv0.y * w;
                acc[2] += xv0.z * w; acc[3] += xv0.w * w;
                acc[4] += xv1.x * w; acc[5] += xv1.y * w;
                acc[6] += xv1.z * w; acc[7] += xv1.w * w;
            }
            #pragma unroll
            for (int g = 0; g < GB; ++g) res[g] += acc[g];
        }
    } else {
        for (int g = 0; g < GB; ++g) {
            int L = lab[g];
            if (L > 0) {
                const float* Wl = Wid + (size_t)(L - 1) * C_DIM * C_DIM;
                float acc = 0.f;
                #pragma unroll 8
                for (int k = 0; k < C_DIM; ++k) acc += xsT[k][g] * Wl[k * C_DIM + t];
                res[g] += acc;
            }
        }
    }
    #pragma unroll
    for (int g = 0; g < GB; ++g) {
        int n = nid[g];
        msgb[(size_t)n * C_DIM + t] = __float2bfloat16(dinv[n] * res[g]);
    }
}

// K7: gather + finalize. One wave per dest node; 4 edges in flight per wave.
// lane = (g, q): g = lane>>4 selects edge slot, q = lane&15 selects channel quad.
__global__ void gather_kernel(const int* __restrict__ s_beg, const int* __restrict__ s_end,
                              const u16* __restrict__ srcrow,
                              const float* __restrict__ dinv,
                              const u32* __restrict__ m32,   // bf16x2-packed msg
                              float* __restrict__ out) {
    int wid  = threadIdx.x >> 6;
    int lane = threadIdx.x & 63;
    int g = lane >> 4;
    int q = lane & 15;
    int c = blockIdx.x * 4 + wid;
    int e0 = s_beg[c], e1 = s_end[c];
    const uint4* m4 = (const uint4*)m32;   // one node = 16 uint4

    float a0[4], a1[4];
    #pragma unroll
    for (int k = 0; k < 4; ++k) { a0[k] = 0.f; a1[k] = 0.f; }

    #define ACC4(U)                                                          \
        a0[0] += __uint_as_float((U).x << 16); a1[0] += __uint_as_float((U).x & 0xffff0000u); \
        a0[1] += __uint_as_float((U).y << 16); a1[1] += __uint_as_float((U).y & 0xffff0000u); \
        a0[2] += __uint_as_float((U).z << 16); a1[2] += __uint_as_float((U).z & 0xffff0000u); \
        a0[3] += __uint_as_float((U).w << 16); a1[3] += __uint_as_float((U).w & 0xffff0000u);

    int e = e0;
    for (; e + 8 <= e1; e += 8) {
        u32 r0 = srcrow[e + g];
        u32 r1 = srcrow[e + 4 + g];
        uint4 u0 = m4[r0 * 16u + (u32)q];
        uint4 u1 = m4[r1 * 16u + (u32)q];
        ACC4(u0);
        ACC4(u1);
    }
    if (e + 4 <= e1) {
        u32 r0 = srcrow[e + g];
        uint4 u0 = m4[r0 * 16u + (u32)q];
        ACC4(u0);
        e += 4;
    }
    if (g == 0) {
        // self-loop message (counted once via edge-slot 0 only)
        uint4 us = m4[(u32)c * 16u + (u32)q];
        ACC4(us);
        // tail (< 4 remaining edges)
        for (; e < e1; ++e) {
            u32 r = srcrow[e];
            uint4 u = m4[r * 16u + (u32)q];
            ACC4(u);
        }
    }
    #undef ACC4

    // reduce the 4 edge-slot groups: lanes l, l^16, l^32, l^48 hold the same quad q
    #pragma unroll
    for (int k = 0; k < 4; ++k) {
        a0[k] += __shfl_xor(a0[k], 16);
        a0[k] += __shfl_xor(a0[k], 32);
        a1[k] += __shfl_xor(a1[k], 16);
        a1[k] += __shfl_xor(a1[k], 32);
    }

    if (lane < 16) {
        float di = dinv[c];
        f32x4 o0, o1;
        o0.x = di * a0[0]; o0.y = di * a1[0]; o0.z = di * a0[1]; o0.w = di * a1[1];
        o1.x = di * a0[2]; o1.y = di * a1[2]; o1.z = di * a0[3]; o1.w = di * a1[3];
        f32x4* op = (f32x4*)(out + ((size_t)c << 7)) + (q << 1);
        __builtin_nontemporal_store(o0, op);
        __builtin_nontemporal_store(o1, op + 1);
    }
}

extern "C" void kernel_launch(void* const* d_in, const int* in_sizes, int n_in,
                              void* d_out, int out_size, void* d_ws, size_t ws_size,
                              hipStream_t stream) {
    const float* x     = (const float*)d_in[0];
    const int*   edge  = (const int*)d_in[1];   // [2][E]
    const int*   id    = (const int*)d_in[2];
    const int*   label = (const int*)d_in[3];
    const float* W     = (const float*)d_in[4];
    const float* Wid   = (const float*)d_in[5];
    float*       out   = (float*)d_out;

    const int* row = edge;
    const int* col = edge + E_EDGES;

    // ws layout:
    // msgb[N*C] bf16 | S[NB*CAP] u32 | srcrow[NB*CAP] u16 | Sr[NB*CAP] u8 |
    // s_beg[N] | s_end[N] | colCursor[NB] | rowCursor[NB] |
    // nodeByLabel[N] | dinv[N] f32 | ZERO{ cnt[N] | labCnt[8] | labCur[8] }
    __hip_bfloat16* msgb = (__hip_bfloat16*)d_ws;
    u32* S           = (u32*)(msgb + (size_t)N_NODES * C_DIM);
    u16* srcrow      = (u16*)(S + (size_t)NB * CAP);
    u8*  Sr          = (u8*)(srcrow + (size_t)NB * CAP);
    int* s_beg       = (int*)(Sr + (size_t)NB * CAP);
    int* s_end       = s_beg + N_NODES;
    int* colCursor   = s_end + N_NODES;
    int* rowCursor   = colCursor + NB;
    int* nodeByLabel = rowCursor + NB;
    float* dinv      = (float*)(nodeByLabel + N_NODES);
    int* cnt         = (int*)(dinv + N_NODES);
    int* labCnt      = cnt + N_NODES;
    int* labCur      = labCnt + 8;

    hipMemsetAsync(cnt, 0, ((size_t)N_NODES + 16) * sizeof(int), stream);

    label_hist_kernel <<<196, 256, 0, stream>>>(label, labCnt, id, cnt, colCursor, rowCursor);
    label_base_kernel <<<1, 64, 0, stream>>>(labCnt, labCur);
    partition_kernel  <<<NP, PT, 0, stream>>>(row, col, colCursor, rowCursor, S, Sr);
    label_fill_kernel <<<196, 256, 0, stream>>>(label, labCur, nodeByLabel);
    csr_deg_kernel    <<<2 * NB, PT, 0, stream>>>(S, Sr, colCursor, rowCursor,
                                                  s_beg, s_end, srcrow, dinv);
    node_msg_kernel   <<<N_NODES / GB, C_DIM, 0, stream>>>(x, cnt, label, dinv, W, Wid,
                                                           nodeByLabel, msgb);
    gather_kernel     <<<N_NODES / 4, 256, 0, stream>>>(s_beg, s_end, srcrow, dinv,
                                                        (const u32*)msgb, out);
}

// Round 9
// 220.481 us; speedup vs baseline: 2.0066x; 1.0483x over previous
//
#include <hip/hip_runtime.h>
#include <hip/hip_bf16.h>

typedef unsigned int   u32;
typedef unsigned short u16;
typedef unsigned char  u8;
typedef float f32x2 __attribute__((ext_vector_type(2)));
typedef float f32x4 __attribute__((ext_vector_type(4)));

#define N_NODES 50000
#define C_DIM   128
#define E_EDGES 1600000
#define NUM_IDX 2048

#define CPB 256                    // cols per coarse bucket (key >> 8)
#define NB  196                    // ceil(N/CPB)
#define CAP 9216                   // padded capacity per bucket (mean 8192, sigma ~90)
#define CHK 8192                   // edges per chunk
#define NP  196                    // ceil(E/CHK)
#define PT  512                    // threads for partition-family kernels
#define EPT 16                     // edges per thread in partition (CHK/PT)
#define GB  8                      // nodes per label-matmul block
#define NLB 98                     // label-stripe blocks of 512 (ceil(N/512))

// LESSONS (journal):
// r5: device-scope global atomics on MI355X are HBM-side RMW (~32B write each;
//     3.2M atomics = 129us, WRITE_SIZE 100MB). Keep histograms in LDS.
// r6: f32x4-casting per-g LDS reads inside GB x k double-unrolled loops spills
//     accumulator state to scratch (WRITE_SIZE 443MB, 4-5x slower).
// r7: node_msg is LDS-issue bound; k-major staging (xsT[k][g]) lets one
//     broadcast b128 pair serve all 8 g per k. node_msg 54 -> ~50us.
// r8: gather is L3-random-access bound (149MB @ ~2.7TB/s = 54us floor).
//     Middle phase = dispatch gaps + small kernels -> fuse into big launches.

// K_A: blocks 0..NP-1 partition edges into padded bucket regions (zero-based
// cursors: reservation adds b*CAP). Blocks NP.. do label/id histogram.
__global__ void part_hist_kernel(const int* __restrict__ row, const int* __restrict__ col,
                                 const int* __restrict__ label, const int* __restrict__ id,
                                 int* __restrict__ colCursor, int* __restrict__ rowCursor,
                                 u32* __restrict__ S, u8* __restrict__ Sr,
                                 int* __restrict__ labCnt, int* __restrict__ cnt) {
    __shared__ int hc[NB], hr[NB], bc[NB], br[NB];
    __shared__ int h8[8];
    int t = threadIdx.x;
    if (blockIdx.x >= NP) {
        // ---- label/id histogram branch (98 blocks x 512 threads) ----
        if (t < 8) h8[t] = 0;
        __syncthreads();
        int n = (blockIdx.x - NP) * PT + t;
        if (n < N_NODES) atomicAdd(&h8[label[n]], 1);
        if (n < NUM_IDX) atomicAdd(&cnt[id[n]], 1);   // blocks 0..3 cover 2048 ids
        __syncthreads();
        if (t < 8 && h8[t] > 0) atomicAdd(&labCnt[t], h8[t]);
        return;
    }
    // ---- partition branch ----
    int p = blockIdx.x;
    for (int i = t; i < NB; i += PT) { hc[i] = 0; hr[i] = 0; }
    __syncthreads();
    int e0 = p * CHK, e1 = min(e0 + CHK, E_EDGES);
    int rr[EPT], cc[EPT];
    #pragma unroll
    for (int i = 0; i < EPT; ++i) {
        int e = e0 + t + i * PT;
        if (e < e1) {
            int r = row[e], c = col[e];
            rr[i] = r; cc[i] = c;
            atomicAdd(&hc[c >> 8], 1);
            atomicAdd(&hr[r >> 8], 1);
        }
    }
    __syncthreads();
    for (int i = t; i < NB; i += PT) {
        bc[i] = (hc[i] > 0) ? (i * CAP + atomicAdd(&colCursor[i], hc[i])) : 0;
        br[i] = (hr[i] > 0) ? (i * CAP + atomicAdd(&rowCursor[i], hr[i])) : 0;
    }
    __syncthreads();
    #pragma unroll
    for (int i = 0; i < EPT; ++i) {
        int e = e0 + t + i * PT;
        if (e < e1) {
            int r = rr[i], c = cc[i];
            int pc = atomicAdd(&bc[c >> 8], 1);
            S[pc] = ((u32)r << 8) | (u32)(c & 255);
            int pr = atomicAdd(&br[r >> 8], 1);
            Sr[pr] = (u8)(r & 255);
        }
    }
}

// K_B: blocks 0..NB-1 fine-CSR; NB..2NB-1 degree/dinv; 2NB.. label_fill
// (in-register label prefix from labCnt + zeroed labOffset reservation).
__global__ void csr_fill_kernel(const u32* __restrict__ S, const u8* __restrict__ Sr,
                                const int* __restrict__ colCursor, const int* __restrict__ rowCursor,
                                int* __restrict__ s_beg, int* __restrict__ s_end,
                                u16* __restrict__ srcrow, float* __restrict__ dinv,
                                const int* __restrict__ label, const int* __restrict__ labCnt,
                                int* __restrict__ labOffset, int* __restrict__ nodeByLabel) {
    __shared__ int h[CPB], cur[CPB], sc[CPB];
    __shared__ int h8[8], base8[8], c28[8];
    int t = threadIdx.x;
    if (blockIdx.x >= 2 * NB) {
        // ---- label_fill branch (98 blocks x 512 threads) ----
        if (t < 8) { h8[t] = 0; c28[t] = 0; }
        __syncthreads();
        int n = (blockIdx.x - 2 * NB) * PT + t;
        int l = 0;
        if (n < N_NODES) { l = label[n]; atomicAdd(&h8[l], 1); }
        __syncthreads();
        if (t < 8 && h8[t] > 0) {
            int lb = 0;                          // labBase[l] = prefix of labCnt
            for (int i = 0; i < t; ++i) lb += labCnt[i];
            base8[t] = lb + atomicAdd(&labOffset[t], h8[t]);
        }
        __syncthreads();
        if (n < N_NODES) {
            int pos = base8[l] + atomicAdd(&c28[l], 1);
            nodeByLabel[pos] = n;
        }
        return;
    }
    if (blockIdx.x >= NB) {
        // ---- degree branch: LDS histogram of Sr bucket -> dinv ----
        int b = blockIdx.x - NB;
        if (t < CPB) h[t] = 0;
        __syncthreads();
        int e0 = b * CAP, e1 = b * CAP + rowCursor[b];
        for (int e = e0 + t; e < e1; e += PT) atomicAdd(&h[Sr[e]], 1);
        __syncthreads();
        if (t < CPB) {
            int n = b * CPB + t;
            if (n < N_NODES) dinv[n] = rsqrtf((float)(h[t] + 1));
        }
        return;
    }
    // ---- fine-CSR branch ----
    int b = blockIdx.x;
    if (t < CPB) h[t] = 0;
    __syncthreads();
    int e0 = b * CAP, e1 = b * CAP + colCursor[b];
    for (int e = e0 + t; e < e1; e += PT) atomicAdd(&h[S[e] & 255u], 1);
    __syncthreads();
    if (t < CPB) sc[t] = h[t];
    __syncthreads();
    for (int off = 1; off < CPB; off <<= 1) {
        int v = 0, a = 0;
        if (t < CPB) { v = sc[t]; a = (t >= off) ? sc[t - off] : 0; }
        __syncthreads();
        if (t < CPB) sc[t] = v + a;
        __syncthreads();
    }
    if (t < CPB) {
        int base = (t == 0) ? 0 : sc[t - 1];
        int gcol = b * CPB + t;
        if (gcol < N_NODES) {
            s_beg[gcol] = e0 + base;
            s_end[gcol] = e0 + base + h[t];
        }
        cur[t] = base;
    }
    __syncthreads();
    for (int e = e0 + t; e < e1; e += PT) {
        u32 v = S[e];
        int pos = atomicAdd(&cur[v & 255u], 1);
        srcrow[e0 + pos] = (u16)(v >> 8);
    }
}

// K6: label-grouped node transform -> bf16 messages (r7 k-major staging).
__global__ void node_msg_kernel(const float* __restrict__ x,
                                const int* __restrict__ cnt,
                                const int* __restrict__ label,
                                const float* __restrict__ dinv,
                                const float* __restrict__ W,
                                const float* __restrict__ Wid,
                                const int* __restrict__ nodeByLabel,
                                __hip_bfloat16* __restrict__ msgb) {
    __shared__ float xsT[C_DIM][GB];       // [k][g], 4 KB
    __shared__ int nid[GB], lab[GB], cc[GB];
    int t = threadIdx.x;
    if (t < GB) {
        int n = nodeByLabel[blockIdx.x * GB + t];
        nid[t] = n; lab[t] = label[n]; cc[t] = cnt[n];
    }
    __syncthreads();
    #pragma unroll
    for (int g = 0; g < GB; ++g)
        xsT[t][g] = __builtin_nontemporal_load(x + (size_t)nid[g] * C_DIM + t);
    __syncthreads();
    for (int g = 0; g < GB; ++g) {          // ego update (~4% of nodes)
        int c = cc[g];
        if (c > 0) {
            float acc = 0.f;
            #pragma unroll 8
            for (int k = 0; k < C_DIM; ++k) acc += xsT[k][g] * W[k * C_DIM + t];
            __syncthreads();
            xsT[t][g] += (float)c * acc;
            __syncthreads();
        }
    }
    float res[GB];
    #pragma unroll
    for (int g = 0; g < GB; ++g) res[g] = xsT[t][g];
    if (lab[0] == lab[GB - 1]) {
        int L = lab[0];
        if (L > 0) {
            const float* Wl = Wid + (size_t)(L - 1) * C_DIM * C_DIM;
            float acc[GB];
            #pragma unroll
            for (int g = 0; g < GB; ++g) acc[g] = 0.f;
            for (int k = 0; k < C_DIM; ++k) {
                float w = Wl[k * C_DIM + t];
                f32x4 xv0 = *(const f32x4*)&xsT[k][0];   // broadcast b128
                f32x4 xv1 = *(const f32x4*)&xsT[k][4];   // broadcast b128
                acc[0] += xv0.x * w; acc[1] += xv0.y * w;
                acc[2] += xv0.z * w; acc[3] += xv0.w * w;
                acc[4] += xv1.x * w; acc[5] += xv1.y * w;
                acc[6] += xv1.z * w; acc[7] += xv1.w * w;
            }
            #pragma unroll
            for (int g = 0; g < GB; ++g) res[g] += acc[g];
        }
    } else {
        for (int g = 0; g < GB; ++g) {
            int L = lab[g];
            if (L > 0) {
                const float* Wl = Wid + (size_t)(L - 1) * C_DIM * C_DIM;
                float acc = 0.f;
                #pragma unroll 8
                for (int k = 0; k < C_DIM; ++k) acc += xsT[k][g] * Wl[k * C_DIM + t];
                res[g] += acc;
            }
        }
    }
    #pragma unroll
    for (int g = 0; g < GB; ++g) {
        int n = nid[g];
        msgb[(size_t)n * C_DIM + t] = __float2bfloat16(dinv[n] * res[g]);
    }
}

// K7: gather + finalize. One wave per dest node; 4 edges in flight per wave.
__global__ void gather_kernel(const int* __restrict__ s_beg, const int* __restrict__ s_end,
                              const u16* __restrict__ srcrow,
                              const float* __restrict__ dinv,
                              const u32* __restrict__ m32,   // bf16x2-packed msg
                              float* __restrict__ out) {
    int wid  = threadIdx.x >> 6;
    int lane = threadIdx.x & 63;
    int g = lane >> 4;
    int q = lane & 15;
    int c = blockIdx.x * 4 + wid;
    int e0 = s_beg[c], e1 = s_end[c];
    const uint4* m4 = (const uint4*)m32;   // one node = 16 uint4

    float a0[4], a1[4];
    #pragma unroll
    for (int k = 0; k < 4; ++k) { a0[k] = 0.f; a1[k] = 0.f; }

    #define ACC4(U)                                                          \
        a0[0] += __uint_as_float((U).x << 16); a1[0] += __uint_as_float((U).x & 0xffff0000u); \
        a0[1] += __uint_as_float((U).y << 16); a1[1] += __uint_as_float((U).y & 0xffff0000u); \
        a0[2] += __uint_as_float((U).z << 16); a1[2] += __uint_as_float((U).z & 0xffff0000u); \
        a0[3] += __uint_as_float((U).w << 16); a1[3] += __uint_as_float((U).w & 0xffff0000u);

    int e = e0;
    for (; e + 8 <= e1; e += 8) {
        u32 r0 = srcrow[e + g];
        u32 r1 = srcrow[e + 4 + g];
        uint4 u0 = m4[r0 * 16u + (u32)q];
        uint4 u1 = m4[r1 * 16u + (u32)q];
        ACC4(u0);
        ACC4(u1);
    }
    if (e + 4 <= e1) {
        u32 r0 = srcrow[e + g];
        uint4 u0 = m4[r0 * 16u + (u32)q];
        ACC4(u0);
        e += 4;
    }
    if (g == 0) {
        // self-loop message (counted once via edge-slot 0 only)
        uint4 us = m4[(u32)c * 16u + (u32)q];
        ACC4(us);
        // tail (< 4 remaining edges)
        for (; e < e1; ++e) {
            u32 r = srcrow[e];
            uint4 u = m4[r * 16u + (u32)q];
            ACC4(u);
        }
    }
    #undef ACC4

    // reduce the 4 edge-slot groups: lanes l, l^16, l^32, l^48 hold the same quad q
    #pragma unroll
    for (int k = 0; k < 4; ++k) {
        a0[k] += __shfl_xor(a0[k], 16);
        a0[k] += __shfl_xor(a0[k], 32);
        a1[k] += __shfl_xor(a1[k], 16);
        a1[k] += __shfl_xor(a1[k], 32);
    }

    if (lane < 16) {
        float di = dinv[c];
        f32x4 o0, o1;
        o0.x = di * a0[0]; o0.y = di * a1[0]; o0.z = di * a0[1]; o0.w = di * a1[1];
        o1.x = di * a0[2]; o1.y = di * a1[2]; o1.z = di * a0[3]; o1.w = di * a1[3];
        f32x4* op = (f32x4*)(out + ((size_t)c << 7)) + (q << 1);
        __builtin_nontemporal_store(o0, op);
        __builtin_nontemporal_store(o1, op + 1);
    }
}

extern "C" void kernel_launch(void* const* d_in, const int* in_sizes, int n_in,
                              void* d_out, int out_size, void* d_ws, size_t ws_size,
                              hipStream_t stream) {
    const float* x     = (const float*)d_in[0];
    const int*   edge  = (const int*)d_in[1];   // [2][E]
    const int*   id    = (const int*)d_in[2];
    const int*   label = (const int*)d_in[3];
    const float* W     = (const float*)d_in[4];
    const float* Wid   = (const float*)d_in[5];
    float*       out   = (float*)d_out;

    const int* row = edge;
    const int* col = edge + E_EDGES;

    // ws layout:
    // msgb[N*C] bf16 | S[NB*CAP] u32 | srcrow[NB*CAP] u16 | Sr[NB*CAP] u8 |
    // s_beg[N] | s_end[N] | nodeByLabel[N] | dinv[N] f32 |
    // ZERO{ cnt[N] | labCnt[8] | labOffset[8] | colCursor[NB] | rowCursor[NB] }
    __hip_bfloat16* msgb = (__hip_bfloat16*)d_ws;
    u32* S           = (u32*)(msgb + (size_t)N_NODES * C_DIM);
    u16* srcrow      = (u16*)(S + (size_t)NB * CAP);
    u8*  Sr          = (u8*)(srcrow + (size_t)NB * CAP);
    int* s_beg       = (int*)(Sr + (size_t)NB * CAP);
    int* s_end       = s_beg + N_NODES;
    int* nodeByLabel = s_end + N_NODES;
    float* dinv      = (float*)(nodeByLabel + N_NODES);
    int* cnt         = (int*)(dinv + N_NODES);
    int* labCnt      = cnt + N_NODES;
    int* labOffset   = labCnt + 8;
    int* colCursor   = labOffset + 8;
    int* rowCursor   = colCursor + NB;

    hipMemsetAsync(cnt, 0, ((size_t)N_NODES + 16 + 2 * NB) * sizeof(int), stream);

    part_hist_kernel<<<NP + NLB, PT, 0, stream>>>(row, col, label, id,
                                                  colCursor, rowCursor, S, Sr, labCnt, cnt);
    csr_fill_kernel <<<2 * NB + NLB, PT, 0, stream>>>(S, Sr, colCursor, rowCursor,
                                                      s_beg, s_end, srcrow, dinv,
                                                      label, labCnt, labOffset, nodeByLabel);
    node_msg_kernel <<<N_NODES / GB, C_DIM, 0, stream>>>(x, cnt, label, dinv, W, Wid,
                                                         nodeByLabel, msgb);
    gather_kernel   <<<N_NODES / 4, 256, 0, stream>>>(s_beg, s_end, srcrow, dinv,
                                                      (const u32*)msgb, out);
}